// Round 7
// baseline (511.413 us; speedup 1.0000x reference)
//
#include <hip/hip_runtime.h>

// MoE, vocab-factorized:
//   T0[e][v][d] = emb0[v] @ W1[e,:1024,:] + b1[e]   (bf16, via prepped E0/W1T)
//   T1[e][v][d] = emb1[v] @ W1[e,1024:,:]           (bf16)
//   G0/G1[v][e] = gating partial logits (f32, bg folded into G0)
//   out[b] = sum_e g_e * (silu(T0[e][x0]+T1[e][x1]) @ W2[e] + b2[e])
// Layer 2 = one fused M=65536,K=4096,N=128 bf16 MFMA GEMM, gates folded into A.
// Round 6: BM=64 / 256-thr / grid-1024 moe_main (4 blocks/CU for cross-block
// overlap of silu-VALU with MFMA), setprio dropped (m190), depth-1 prefetch.

typedef __attribute__((ext_vector_type(8))) short short8;
typedef __attribute__((ext_vector_type(4))) float f32x4;

static __device__ __forceinline__ unsigned short f2b(float f) {
  unsigned int u = __builtin_bit_cast(unsigned int, f);
  u += 0x7fffu + ((u >> 16) & 1u);  // RNE to bf16
  return (unsigned short)(u >> 16);
}
static __device__ __forceinline__ float bflo(unsigned int u) {
  return __builtin_bit_cast(float, u << 16);
}
static __device__ __forceinline__ float bfhi(unsigned int u) {
  return __builtin_bit_cast(float, u & 0xffff0000u);
}
// HW packed f32->bf16 (RNE): low16 = cvt(a), high16 = cvt(b)
static __device__ __forceinline__ unsigned int cvtpk(float a, float b) {
  unsigned int r;
  asm("v_cvt_pk_bf16_f32 %0, %1, %2" : "=v"(r) : "v"(a), "v"(b));
  return r;
}

// barrier WITHOUT vmcnt drain: LDS ops ordered, global prefetch stays in flight
#define BARRIER() do { asm volatile("s_waitcnt lgkmcnt(0)" ::: "memory"); \
                       __builtin_amdgcn_s_barrier(); } while (0)

// ---------------- merged prep kernel ----------------
// grid 3712 x 256thr:
//   [0,1024)    prep_g   : gating tables G0/G1 (f32, bg folded into G0)
//   [1024,1536) prep_emb : emb f32 -> bf16 E0/E1
//   [1536,1664) prep_w2  : W2 [4][1024][128] -> W2T [128o][4096k] bf16
//   [1664,3712) prep_w1t : W1 [4][2048][1024] -> W1T bf16 [8z][1024d][1024k]
__global__ void prep_all(const float* __restrict__ emb0, const float* __restrict__ emb1,
                         const float* __restrict__ Wg, const float* __restrict__ bg,
                         const float* __restrict__ W2, const float* __restrict__ W1,
                         float* __restrict__ G0, float* __restrict__ G1,
                         unsigned short* __restrict__ E0, unsigned short* __restrict__ E1,
                         unsigned short* __restrict__ W2T, unsigned short* __restrict__ W1T) {
  __shared__ __align__(16) char sm[16640];
  const int bid = blockIdx.x;
  const int tid = threadIdx.x;
  if (bid < 1024) {  // ---- prep_g ----
    float (*red)[256] = (float(*)[256])sm;
    const int half = bid >> 9, v = bid & 511;
    const float* __restrict__ emb = half ? emb1 : emb0;
    const float* __restrict__ wg = Wg + (size_t)half * 1024 * 4;
    float a0 = 0.f, a1 = 0.f, a2 = 0.f, a3 = 0.f;
    for (int i = tid; i < 1024; i += 256) {
      const float ev = emb[(size_t)v * 1024 + i];
      const float4 w = *(const float4*)(wg + (size_t)i * 4);
      a0 += ev * w.x; a1 += ev * w.y; a2 += ev * w.z; a3 += ev * w.w;
    }
    red[0][tid] = a0; red[1][tid] = a1; red[2][tid] = a2; red[3][tid] = a3;
    __syncthreads();
    for (int s = 128; s > 0; s >>= 1) {
      if (tid < s) {
        red[0][tid] += red[0][tid + s]; red[1][tid] += red[1][tid + s];
        red[2][tid] += red[2][tid + s]; red[3][tid] += red[3][tid + s];
      }
      __syncthreads();
    }
    if (tid < 4) {
      const float val = red[tid][0] + (half == 0 ? bg[tid] : 0.f);
      (half ? G1 : G0)[(size_t)v * 4 + tid] = val;
    }
  } else if (bid < 1536) {  // ---- prep_emb ----
    const int idx = bid - 1024;
    const int half = idx >> 8, blk = idx & 255;
    const float* __restrict__ src = half ? emb1 : emb0;
    unsigned short* __restrict__ dst = half ? E1 : E0;
    const size_t base = (size_t)blk * 2048 + (size_t)tid * 8;
    const float4 lo = *(const float4*)(src + base);
    const float4 hi = *(const float4*)(src + base + 4);
    uint4 o;
    o.x = cvtpk(lo.x, lo.y); o.y = cvtpk(lo.z, lo.w);
    o.z = cvtpk(hi.x, hi.y); o.w = cvtpk(hi.z, hi.w);
    *(uint4*)(dst + base) = o;
  } else if (bid < 1664) {  // ---- prep_w2 ----
    float (*st)[65] = (float(*)[65])sm;
    const int idx = bid - 1536;
    const int kt = idx & 63, ot = idx >> 6;
    for (int it = 0; it < 16; ++it) {
      const int i2 = it * 256 + tid;
      const int k = i2 >> 6, o = i2 & 63;
      st[k][o] = W2[(size_t)(kt * 64 + k) * 128 + ot * 64 + o];
    }
    __syncthreads();
    for (int it = 0; it < 4; ++it) {
      const int i2 = it * 256 + tid;
      const int o = i2 >> 4, c = i2 & 15;
      const unsigned int p0 = cvtpk(st[c * 4 + 0][o], st[c * 4 + 1][o]);
      const unsigned int p1 = cvtpk(st[c * 4 + 2][o], st[c * 4 + 3][o]);
      *(uint2*)(W2T + (size_t)(ot * 64 + o) * 4096 + kt * 64 + c * 4) = make_uint2(p0, p1);
    }
  } else {  // ---- prep_w1t ----
    float (*st)[65] = (float(*)[65])sm;
    const int idx = bid - 1664;
    const int z = idx >> 8, xx = idx & 255;
    const int kt = xx >> 4, dt = xx & 15;
    const int e = z >> 1, half = z & 1;
    const int r = tid >> 2, cg = (tid & 3) * 16;
    const float* src = W1 + ((size_t)e * 2048 + half * 1024 + kt * 64 + r) * 1024 + dt * 64 + cg;
#pragma unroll
    for (int j = 0; j < 4; ++j) {
      const float4 v = *(const float4*)(src + j * 4);
      st[r][cg + j * 4 + 0] = v.x; st[r][cg + j * 4 + 1] = v.y;
      st[r][cg + j * 4 + 2] = v.z; st[r][cg + j * 4 + 3] = v.w;
    }
    __syncthreads();
    const int dr = tid >> 2, kb = (tid & 3) * 16;
    uint4 o0, o1;
    o0.x = cvtpk(st[kb + 0][dr], st[kb + 1][dr]);
    o0.y = cvtpk(st[kb + 2][dr], st[kb + 3][dr]);
    o0.z = cvtpk(st[kb + 4][dr], st[kb + 5][dr]);
    o0.w = cvtpk(st[kb + 6][dr], st[kb + 7][dr]);
    o1.x = cvtpk(st[kb + 8][dr], st[kb + 9][dr]);
    o1.y = cvtpk(st[kb + 10][dr], st[kb + 11][dr]);
    o1.z = cvtpk(st[kb + 12][dr], st[kb + 13][dr]);
    o1.w = cvtpk(st[kb + 14][dr], st[kb + 15][dr]);
    unsigned short* dst = W1T + ((size_t)z * 1024 + dt * 64 + dr) * 1024 + kt * 64 + kb;
    *(uint4*)dst = o0;
    *(uint4*)(dst + 8) = o1;
  }
}

// ---------------- expert tables: per z, (512v x 1024k) @ (1024k x 1024d) ----------------
// BM=64(v) x BN=64(d), BK=64; grid 1024 = z8 * vt8 * dt16; 256 thr (4 waves, 32x32 each)
__launch_bounds__(256, 4)
__global__ void build_tables(const unsigned short* __restrict__ E0,
                             const unsigned short* __restrict__ E1,
                             const unsigned short* __restrict__ W1T,
                             const float* __restrict__ b1,
                             unsigned short* __restrict__ T0, unsigned short* __restrict__ T1) {
  __shared__ __align__(16) unsigned short At[64 * 64];  // [v][k] swizzled, 8KB
  __shared__ __align__(16) unsigned short Bt[64 * 64];  // [d][k] swizzled, 8KB

  const int bid = blockIdx.x;
  const int z = bid >> 7, rem = bid & 127;
  const int vt = rem >> 4, dt = rem & 15;
  const int e = z >> 1, half = z & 1;
  const unsigned short* __restrict__ E = half ? E1 : E0;
  const unsigned short* __restrict__ Wp = W1T + (size_t)z * 1024 * 1024;
  unsigned short* __restrict__ Tout = (half ? T1 : T0) + (size_t)e * 512 * 1024;

  const int tid = threadIdx.x, lane = tid & 63, wave = tid >> 6;
  const int wm = wave >> 1, wn = wave & 1;

  // staging: 4 thr/row, 32B each (rows = A's v / B's d)
  const int arow = tid >> 2, ac = tid & 3;
  int wOff[2];
#pragma unroll
  for (int i = 0; i < 2; ++i)
    wOff[i] = arow * 128 + ((ac * 32 + i * 16) ^ ((arow & 7) << 4));
  const unsigned short* aSrc = E + (size_t)(vt * 64 + arow) * 1024 + ac * 16;
  const unsigned short* bSrc = Wp + (size_t)(dt * 64 + arow) * 1024 + ac * 16;

  const int kq = (lane >> 4) * 16;
  int rAoff[2], rAsw[2], rBoff[2], rBsw[2];
#pragma unroll
  for (int mi = 0; mi < 2; ++mi) {
    const int ra = wm * 32 + mi * 16 + (lane & 15);
    rAoff[mi] = ra * 128; rAsw[mi] = (ra & 7) << 4;
    const int cb = wn * 32 + mi * 16 + (lane & 15);
    rBoff[mi] = cb * 128; rBsw[mi] = (cb & 7) << 4;
  }

  f32x4 acc[2][2] = {};
  uint4 eaA[2], ebA[2];

  auto issue = [&](int kt) {
    const int k0 = kt * 64;
    eaA[0] = *(const uint4*)(aSrc + k0); eaA[1] = *(const uint4*)(aSrc + k0 + 8);
    ebA[0] = *(const uint4*)(bSrc + k0); ebA[1] = *(const uint4*)(bSrc + k0 + 8);
  };
  auto mfmaStep = [&]() {
#pragma unroll
    for (int kk = 0; kk < 2; ++kk) {
      const int kb = kk * 64 + kq;
      short8 af[2], bfr[2];
#pragma unroll
      for (int mi = 0; mi < 2; ++mi)
        af[mi] = *(const short8*)((char*)At + rAoff[mi] + (kb ^ rAsw[mi]));
#pragma unroll
      for (int ni = 0; ni < 2; ++ni)
        bfr[ni] = *(const short8*)((char*)Bt + rBoff[ni] + (kb ^ rBsw[ni]));
#pragma unroll
      for (int mi = 0; mi < 2; ++mi)
#pragma unroll
        for (int ni = 0; ni < 2; ++ni)
          acc[mi][ni] = __builtin_amdgcn_mfma_f32_16x16x32_bf16(af[mi], bfr[ni], acc[mi][ni], 0, 0, 0);
    }
  };

  issue(0);
  for (int kt = 0; kt < 16; ++kt) {
    BARRIER();  // prior frag reads done
#pragma unroll
    for (int i = 0; i < 2; ++i) {
      *(uint4*)((char*)At + wOff[i]) = eaA[i];
      *(uint4*)((char*)Bt + wOff[i]) = ebA[i];
    }
    if (kt < 15) issue(kt + 1);
    BARRIER();  // writes visible
    mfmaStep();
  }

  // epilogue: + b1 (half 0 only), bf16, LDS-bounce for coalesced stores
  const float* bb = b1 + (size_t)e * 1024;
  unsigned short* fs = At;  // 64x64 ushort = 8KB
  BARRIER();
#pragma unroll
  for (int ni = 0; ni < 2; ++ni) {
    const int lc = wn * 32 + ni * 16 + (lane & 15);
    const float bias = (half == 0) ? bb[dt * 64 + lc] : 0.f;
#pragma unroll
    for (int mi = 0; mi < 2; ++mi) {
      const int r0 = wm * 32 + mi * 16 + ((lane >> 4) << 2);
      const f32x4 a = acc[mi][ni];
#pragma unroll
      for (int j = 0; j < 4; ++j) fs[(r0 + j) * 64 + lc] = f2b(a[j] + bias);
    }
  }
  BARRIER();
  {
    const int r = tid >> 2, c = (tid & 3) * 16;
    const uint4 w0 = *(const uint4*)(fs + r * 64 + c);
    const uint4 w1 = *(const uint4*)(fs + r * 64 + c + 8);
    unsigned short* op = Tout + (size_t)(vt * 64 + r) * 1024 + dt * 64 + c;
    *(uint4*)op = w0;
    *(uint4*)(op + 8) = w1;
  }
}

// ---------------- main fused kernel: gather + silu + gate + GEMM ----------------
// BM=64 tokens, BN=128 out, BK=64; 256 thr (4 waves: wm2 x wn2, mi=2, ni=4)
// grid 1024 -> 4 blocks/CU: cross-block overlap of silu-VALU with MFMA.
__launch_bounds__(256, 4)
__global__ void moe_main(const int* __restrict__ X,
                         const unsigned short* __restrict__ T0,
                         const unsigned short* __restrict__ T1,
                         const unsigned short* __restrict__ W2T,
                         const float* __restrict__ G0,
                         const float* __restrict__ G1,
                         const float* __restrict__ b2v,
                         float* __restrict__ out) {
  __shared__ __align__(16) char smem[26112];
  unsigned short* At = (unsigned short*)smem;            // 8 KB  [64 tok][64 k]
  unsigned short* Bt = (unsigned short*)(smem + 8192);   // 16 KB [128 out][64 k]
  float* gl = (float*)(smem + 24576);                    // 1 KB
  int* xs0 = (int*)(smem + 25600);                       // 256 B
  int* xs1 = (int*)(smem + 25856);                       // 256 B

  const int tid = threadIdx.x, lane = tid & 63, wave = tid >> 6;
  const int wm = wave >> 1, wn = wave & 1;
  int bid = blockIdx.x;
  bid = (bid & 7) * 128 + (bid >> 3);  // XCD swizzle (1024 % 8 == 0, bijective)
  const int b0 = bid * 64;

  if (tid < 64) {
    const int b = b0 + tid;
    const int x0 = X[2 * b], x1 = X[2 * b + 1];
    xs0[tid] = x0; xs1[tid] = x1;
    const float4 l0 = *(const float4*)(G0 + 4 * x0);
    const float4 l1 = *(const float4*)(G1 + 4 * x1);
    const float z0 = l0.x + l1.x, z1 = l0.y + l1.y;
    const float z2 = l0.z + l1.z, z3 = l0.w + l1.w;
    const float m = fmaxf(fmaxf(z0, z1), fmaxf(z2, z3));
    const float e0 = __expf(z0 - m), e1 = __expf(z1 - m);
    const float e2 = __expf(z2 - m), e3 = __expf(z3 - m);
    const float inv = __builtin_amdgcn_rcpf(e0 + e1 + e2 + e3);
    *(float4*)(&gl[4 * tid]) = make_float4(e0 * inv, e1 * inv, e2 * inv, e3 * inv);
  }
  __syncthreads();

  // A staging: 4 thr/row over 64 rows, 32B (16 elems) per thread
  const int arow = tid >> 2, ac = tid & 3;
  const int sx0 = xs0[arow], sx1 = xs1[arow];
  const float4 grow = *(const float4*)(&gl[4 * arow]);
  int wOffA[2];
#pragma unroll
  for (int i = 0; i < 2; ++i)
    wOffA[i] = arow * 128 + ((ac * 32 + i * 16) ^ ((arow & 7) << 4));
  // B staging: 2 thr/row over 128 rows, 64B (32 elems) per thread
  const int brow = tid >> 1, bc = tid & 1;
  int wOffB[4];
#pragma unroll
  for (int i = 0; i < 4; ++i)
    wOffB[i] = brow * 128 + ((bc * 64 + i * 16) ^ ((brow & 7) << 4));

  // frag read offsets
  const int kq = (lane >> 4) * 16;
  int rAoff[2], rAsw[2], rBoff[4], rBsw[4];
#pragma unroll
  for (int mi = 0; mi < 2; ++mi) {
    const int ra = wm * 32 + mi * 16 + (lane & 15);
    rAoff[mi] = ra * 128; rAsw[mi] = (ra & 7) << 4;
  }
#pragma unroll
  for (int ni = 0; ni < 4; ++ni) {
    const int cb = wn * 64 + ni * 16 + (lane & 15);
    rBoff[ni] = cb * 128; rBsw[ni] = (cb & 7) << 4;
  }

  f32x4 acc[2][4] = {};
  uint4 ua[2], ub[2], bw[4];

  auto issueA = [&](int t) {
    const int e = t >> 4, d0 = (t & 15) << 6;
    const unsigned short* p0 = T0 + (((size_t)(e * 512 + sx0)) << 10) + d0 + ac * 16;
    const unsigned short* p1 = T1 + (((size_t)(e * 512 + sx1)) << 10) + d0 + ac * 16;
    ua[0] = *(const uint4*)p0; ua[1] = *(const uint4*)(p0 + 8);
    ub[0] = *(const uint4*)p1; ub[1] = *(const uint4*)(p1 + 8);
  };
  auto issueB = [&](int t) {
    const unsigned short* pb = W2T + (size_t)brow * 4096 + t * 64 + bc * 32;
#pragma unroll
    for (int i = 0; i < 4; ++i) bw[i] = *(const uint4*)(pb + i * 8);
  };
  auto siluPack = [&](float g, uint4* sw) {
#pragma unroll
    for (int i = 0; i < 2; ++i) {
      const unsigned int uu[4] = {ua[i].x, ua[i].y, ua[i].z, ua[i].w};
      const unsigned int vv[4] = {ub[i].x, ub[i].y, ub[i].z, ub[i].w};
      unsigned int w[4];
#pragma unroll
      for (int p = 0; p < 4; ++p) {
        const float f0 = bflo(uu[p]) + bflo(vv[p]);
        const float f1 = bfhi(uu[p]) + bfhi(vv[p]);
        const float s0 = g * f0 * __builtin_amdgcn_rcpf(1.f + __expf(-f0));
        const float s1 = g * f1 * __builtin_amdgcn_rcpf(1.f + __expf(-f1));
        w[p] = cvtpk(s0, s1);
      }
      sw[i] = uint4{w[0], w[1], w[2], w[3]};
    }
  };
  auto mfmaStep = [&]() {
#pragma unroll
    for (int kk = 0; kk < 2; ++kk) {
      const int kb = kk * 64 + kq;
      short8 af[2], bfr[4];
#pragma unroll
      for (int mi = 0; mi < 2; ++mi)
        af[mi] = *(const short8*)((char*)At + rAoff[mi] + (kb ^ rAsw[mi]));
#pragma unroll
      for (int ni = 0; ni < 4; ++ni)
        bfr[ni] = *(const short8*)((char*)Bt + rBoff[ni] + (kb ^ rBsw[ni]));
#pragma unroll
      for (int mi = 0; mi < 2; ++mi)
#pragma unroll
        for (int ni = 0; ni < 4; ++ni)
          acc[mi][ni] = __builtin_amdgcn_mfma_f32_16x16x32_bf16(af[mi], bfr[ni], acc[mi][ni], 0, 0, 0);
    }
  };
  auto gsel = [&](int t) -> float {
    const int e = t >> 4;
    return (e == 0) ? grow.x : (e == 1) ? grow.y : (e == 2) ? grow.z : grow.w;
  };

  issueA(0);
  issueB(0);
  for (int t = 0; t < 64; ++t) {
    uint4 sa[2];
    siluPack(gsel(t), sa);
    if (t < 63) issueA(t + 1);   // ua/ub free after siluPack; loads fly over barrier
    BARRIER();  // #1: all waves' frag reads of previous tile complete
    *(uint4*)((char*)At + wOffA[0]) = sa[0];
    *(uint4*)((char*)At + wOffA[1]) = sa[1];
#pragma unroll
    for (int i = 0; i < 4; ++i) *(uint4*)((char*)Bt + wOffB[i]) = bw[i];
    if (t < 63) issueB(t + 1);
    BARRIER();  // #2: writes visible
    mfmaStep();
  }

  // ---- epilogue: + sum_e g_e*b2[e][o] into acc, then LDS-bounce coalesced store ----
#pragma unroll
  for (int ni = 0; ni < 4; ++ni) {
    const int col = wn * 64 + ni * 16 + (lane & 15);
    const float c0 = b2v[col], c1 = b2v[128 + col];
    const float c2 = b2v[256 + col], c3 = b2v[384 + col];
#pragma unroll
    for (int mi = 0; mi < 2; ++mi) {
#pragma unroll
      for (int j = 0; j < 4; ++j) {
        const int row = wm * 32 + mi * 16 + ((lane >> 4) << 2) + j;
        const float4 g = *(const float4*)(&gl[4 * row]);
        acc[mi][ni][j] += g.x * c0 + g.y * c1 + g.z * c2 + g.w * c3;
      }
    }
  }
  float* fs = (float*)smem;  // 32 x 132 f32 = 16.9KB (At+Bt region; gl preserved)
#pragma unroll
  for (int p = 0; p < 2; ++p) {
    BARRIER();  // MFMA frag reads (p=0) / pass-0 readbacks (p=1) complete
    if (wm == p) {
#pragma unroll
      for (int ni = 0; ni < 4; ++ni) {
        const int col = wn * 64 + ni * 16 + (lane & 15);
#pragma unroll
        for (int mi = 0; mi < 2; ++mi) {
          const int r0 = mi * 16 + ((lane >> 4) << 2);
          const f32x4 a = acc[mi][ni];
#pragma unroll
          for (int j = 0; j < 4; ++j) fs[(r0 + j) * 132 + col] = a[j];
        }
      }
    }
    BARRIER();
    const int r = tid >> 3, c0 = (tid & 7) * 16;
    const float4 v0 = *(const float4*)(fs + r * 132 + c0);
    const float4 v1 = *(const float4*)(fs + r * 132 + c0 + 4);
    const float4 v2 = *(const float4*)(fs + r * 132 + c0 + 8);
    const float4 v3 = *(const float4*)(fs + r * 132 + c0 + 12);
    float* op = out + (size_t)(b0 + p * 32 + r) * 128 + c0;
    *(float4*)op = v0;
    *(float4*)(op + 4) = v1;
    *(float4*)(op + 8) = v2;
    *(float4*)(op + 12) = v3;
  }
}

extern "C" void kernel_launch(void* const* d_in, const int* in_sizes, int n_in,
                              void* d_out, int out_size, void* d_ws, size_t ws_size,
                              hipStream_t stream) {
  const int*   X    = (const int*)  d_in[0];
  const float* emb0 = (const float*)d_in[1];
  const float* emb1 = (const float*)d_in[2];
  const float* W1   = (const float*)d_in[3];
  const float* b1   = (const float*)d_in[4];
  const float* W2   = (const float*)d_in[5];
  const float* b2   = (const float*)d_in[6];
  const float* Wg   = (const float*)d_in[7];
  const float* bg   = (const float*)d_in[8];
  float* out = (float*)d_out;

  char* ws = (char*)d_ws;
  const size_t MB = 1024 * 1024;
  unsigned short* T0  = (unsigned short*)(ws);             // 4 MB
  unsigned short* T1  = (unsigned short*)(ws + 4 * MB);    // 4 MB
  unsigned short* W2T = (unsigned short*)(ws + 8 * MB);    // 1 MB
  float* G0 = (float*)(ws + 9 * MB);                       // 8 KB
  float* G1 = (float*)(ws + 9 * MB + 8192);                // 8 KB
  unsigned short* E0  = (unsigned short*)(ws + 10 * MB);   // 1 MB
  unsigned short* E1  = (unsigned short*)(ws + 11 * MB);   // 1 MB
  unsigned short* W1T = (unsigned short*)(ws + 12 * MB);   // 16 MB

  hipLaunchKernelGGL(prep_all, dim3(3712), dim3(256), 0, stream,
                     emb0, emb1, Wg, bg, W2, W1, G0, G1, E0, E1, W2T, W1T);
  hipLaunchKernelGGL(build_tables, dim3(1024), dim3(256), 0, stream, E0, E1, W1T, b1, T0, T1);
  hipLaunchKernelGGL(moe_main, dim3(1024), dim3(256), 0, stream, X, T0, T1, W2T, G0, G1, b2, out);
}

// Round 11
// 369.288 us; speedup vs baseline: 1.3849x; 1.3849x over previous
//
#include <hip/hip_runtime.h>

// MoE, vocab-factorized. Round 8 = round-3 moe_main structure (207us, proven)
// + cvt_pk silu packing + coalesced LDS-bounce epilogue. Nothing else changed.

typedef __attribute__((ext_vector_type(8))) short short8;
typedef __attribute__((ext_vector_type(4))) float f32x4;

static __device__ __forceinline__ unsigned short f2b(float f) {
  unsigned int u = __builtin_bit_cast(unsigned int, f);
  u += 0x7fffu + ((u >> 16) & 1u);  // RNE to bf16
  return (unsigned short)(u >> 16);
}
static __device__ __forceinline__ float bflo(unsigned int u) {
  return __builtin_bit_cast(float, u << 16);
}
static __device__ __forceinline__ float bfhi(unsigned int u) {
  return __builtin_bit_cast(float, u & 0xffff0000u);
}
static __device__ __forceinline__ unsigned int cvtpk(float a, float b) {
  unsigned int r;
  asm("v_cvt_pk_bf16_f32 %0, %1, %2" : "=v"(r) : "v"(a), "v"(b));
  return r;
}

// barrier WITHOUT vmcnt drain: LDS ops ordered, global prefetch stays in flight
#define BARRIER() do { asm volatile("s_waitcnt lgkmcnt(0)" ::: "memory"); \
                       __builtin_amdgcn_s_barrier(); } while (0)

// ---------------- merged prep kernel (unchanged from r6) ----------------
__global__ void prep_all(const float* __restrict__ emb0, const float* __restrict__ emb1,
                         const float* __restrict__ Wg, const float* __restrict__ bg,
                         const float* __restrict__ W2, const float* __restrict__ W1,
                         float* __restrict__ G0, float* __restrict__ G1,
                         unsigned short* __restrict__ E0, unsigned short* __restrict__ E1,
                         unsigned short* __restrict__ W2T, unsigned short* __restrict__ W1T) {
  __shared__ __align__(16) char sm[16640];
  const int bid = blockIdx.x;
  const int tid = threadIdx.x;
  if (bid < 1024) {  // ---- prep_g ----
    float (*red)[256] = (float(*)[256])sm;
    const int half = bid >> 9, v = bid & 511;
    const float* __restrict__ emb = half ? emb1 : emb0;
    const float* __restrict__ wg = Wg + (size_t)half * 1024 * 4;
    float a0 = 0.f, a1 = 0.f, a2 = 0.f, a3 = 0.f;
    for (int i = tid; i < 1024; i += 256) {
      const float ev = emb[(size_t)v * 1024 + i];
      const float4 w = *(const float4*)(wg + (size_t)i * 4);
      a0 += ev * w.x; a1 += ev * w.y; a2 += ev * w.z; a3 += ev * w.w;
    }
    red[0][tid] = a0; red[1][tid] = a1; red[2][tid] = a2; red[3][tid] = a3;
    __syncthreads();
    for (int s = 128; s > 0; s >>= 1) {
      if (tid < s) {
        red[0][tid] += red[0][tid + s]; red[1][tid] += red[1][tid + s];
        red[2][tid] += red[2][tid + s]; red[3][tid] += red[3][tid + s];
      }
      __syncthreads();
    }
    if (tid < 4) {
      const float val = red[tid][0] + (half == 0 ? bg[tid] : 0.f);
      (half ? G1 : G0)[(size_t)v * 4 + tid] = val;
    }
  } else if (bid < 1536) {  // ---- prep_emb ----
    const int idx = bid - 1024;
    const int half = idx >> 8, blk = idx & 255;
    const float* __restrict__ src = half ? emb1 : emb0;
    unsigned short* __restrict__ dst = half ? E1 : E0;
    const size_t base = (size_t)blk * 2048 + (size_t)tid * 8;
    const float4 lo = *(const float4*)(src + base);
    const float4 hi = *(const float4*)(src + base + 4);
    uint4 o;
    o.x = cvtpk(lo.x, lo.y); o.y = cvtpk(lo.z, lo.w);
    o.z = cvtpk(hi.x, hi.y); o.w = cvtpk(hi.z, hi.w);
    *(uint4*)(dst + base) = o;
  } else if (bid < 1664) {  // ---- prep_w2 ----
    float (*st)[65] = (float(*)[65])sm;
    const int idx = bid - 1536;
    const int kt = idx & 63, ot = idx >> 6;
    for (int it = 0; it < 16; ++it) {
      const int i2 = it * 256 + tid;
      const int k = i2 >> 6, o = i2 & 63;
      st[k][o] = W2[(size_t)(kt * 64 + k) * 128 + ot * 64 + o];
    }
    __syncthreads();
    for (int it = 0; it < 4; ++it) {
      const int i2 = it * 256 + tid;
      const int o = i2 >> 4, c = i2 & 15;
      const unsigned int p0 = cvtpk(st[c * 4 + 0][o], st[c * 4 + 1][o]);
      const unsigned int p1 = cvtpk(st[c * 4 + 2][o], st[c * 4 + 3][o]);
      *(uint2*)(W2T + (size_t)(ot * 64 + o) * 4096 + kt * 64 + c * 4) = make_uint2(p0, p1);
    }
  } else {  // ---- prep_w1t ----
    float (*st)[65] = (float(*)[65])sm;
    const int idx = bid - 1664;
    const int z = idx >> 8, xx = idx & 255;
    const int kt = xx >> 4, dt = xx & 15;
    const int e = z >> 1, half = z & 1;
    const int r = tid >> 2, cg = (tid & 3) * 16;
    const float* src = W1 + ((size_t)e * 2048 + half * 1024 + kt * 64 + r) * 1024 + dt * 64 + cg;
#pragma unroll
    for (int j = 0; j < 4; ++j) {
      const float4 v = *(const float4*)(src + j * 4);
      st[r][cg + j * 4 + 0] = v.x; st[r][cg + j * 4 + 1] = v.y;
      st[r][cg + j * 4 + 2] = v.z; st[r][cg + j * 4 + 3] = v.w;
    }
    __syncthreads();
    const int dr = tid >> 2, kb = (tid & 3) * 16;
    uint4 o0, o1;
    o0.x = cvtpk(st[kb + 0][dr], st[kb + 1][dr]);
    o0.y = cvtpk(st[kb + 2][dr], st[kb + 3][dr]);
    o0.z = cvtpk(st[kb + 4][dr], st[kb + 5][dr]);
    o0.w = cvtpk(st[kb + 6][dr], st[kb + 7][dr]);
    o1.x = cvtpk(st[kb + 8][dr], st[kb + 9][dr]);
    o1.y = cvtpk(st[kb + 10][dr], st[kb + 11][dr]);
    o1.z = cvtpk(st[kb + 12][dr], st[kb + 13][dr]);
    o1.w = cvtpk(st[kb + 14][dr], st[kb + 15][dr]);
    unsigned short* dst = W1T + ((size_t)z * 1024 + dt * 64 + dr) * 1024 + kt * 64 + kb;
    *(uint4*)dst = o0;
    *(uint4*)(dst + 8) = o1;
  }
}

// ---------------- build_tables (unchanged from r6) ----------------
__launch_bounds__(256, 4)
__global__ void build_tables(const unsigned short* __restrict__ E0,
                             const unsigned short* __restrict__ E1,
                             const unsigned short* __restrict__ W1T,
                             const float* __restrict__ b1,
                             unsigned short* __restrict__ T0, unsigned short* __restrict__ T1) {
  __shared__ __align__(16) unsigned short At[64 * 64];
  __shared__ __align__(16) unsigned short Bt[64 * 64];

  const int bid = blockIdx.x;
  const int z = bid >> 7, rem = bid & 127;
  const int vt = rem >> 4, dt = rem & 15;
  const int e = z >> 1, half = z & 1;
  const unsigned short* __restrict__ E = half ? E1 : E0;
  const unsigned short* __restrict__ Wp = W1T + (size_t)z * 1024 * 1024;
  unsigned short* __restrict__ Tout = (half ? T1 : T0) + (size_t)e * 512 * 1024;

  const int tid = threadIdx.x, lane = tid & 63, wave = tid >> 6;
  const int wm = wave >> 1, wn = wave & 1;

  const int arow = tid >> 2, ac = tid & 3;
  int wOff[2];
#pragma unroll
  for (int i = 0; i < 2; ++i)
    wOff[i] = arow * 128 + ((ac * 32 + i * 16) ^ ((arow & 7) << 4));
  const unsigned short* aSrc = E + (size_t)(vt * 64 + arow) * 1024 + ac * 16;
  const unsigned short* bSrc = Wp + (size_t)(dt * 64 + arow) * 1024 + ac * 16;

  const int kq = (lane >> 4) * 16;
  int rAoff[2], rAsw[2], rBoff[2], rBsw[2];
#pragma unroll
  for (int mi = 0; mi < 2; ++mi) {
    const int ra = wm * 32 + mi * 16 + (lane & 15);
    rAoff[mi] = ra * 128; rAsw[mi] = (ra & 7) << 4;
    const int cb = wn * 32 + mi * 16 + (lane & 15);
    rBoff[mi] = cb * 128; rBsw[mi] = (cb & 7) << 4;
  }

  f32x4 acc[2][2] = {};
  uint4 eaA[2], ebA[2];

  auto issue = [&](int kt) {
    const int k0 = kt * 64;
    eaA[0] = *(const uint4*)(aSrc + k0); eaA[1] = *(const uint4*)(aSrc + k0 + 8);
    ebA[0] = *(const uint4*)(bSrc + k0); ebA[1] = *(const uint4*)(bSrc + k0 + 8);
  };
  auto mfmaStep = [&]() {
#pragma unroll
    for (int kk = 0; kk < 2; ++kk) {
      const int kb = kk * 64 + kq;
      short8 af[2], bfr[2];
#pragma unroll
      for (int mi = 0; mi < 2; ++mi)
        af[mi] = *(const short8*)((char*)At + rAoff[mi] + (kb ^ rAsw[mi]));
#pragma unroll
      for (int ni = 0; ni < 2; ++ni)
        bfr[ni] = *(const short8*)((char*)Bt + rBoff[ni] + (kb ^ rBsw[ni]));
#pragma unroll
      for (int mi = 0; mi < 2; ++mi)
#pragma unroll
        for (int ni = 0; ni < 2; ++ni)
          acc[mi][ni] = __builtin_amdgcn_mfma_f32_16x16x32_bf16(af[mi], bfr[ni], acc[mi][ni], 0, 0, 0);
    }
  };

  issue(0);
  for (int kt = 0; kt < 16; ++kt) {
    BARRIER();
#pragma unroll
    for (int i = 0; i < 2; ++i) {
      *(uint4*)((char*)At + wOff[i]) = eaA[i];
      *(uint4*)((char*)Bt + wOff[i]) = ebA[i];
    }
    if (kt < 15) issue(kt + 1);
    BARRIER();
    mfmaStep();
  }

  const float* bb = b1 + (size_t)e * 1024;
  unsigned short* fs = At;
  BARRIER();
#pragma unroll
  for (int ni = 0; ni < 2; ++ni) {
    const int lc = wn * 32 + ni * 16 + (lane & 15);
    const float bias = (half == 0) ? bb[dt * 64 + lc] : 0.f;
#pragma unroll
    for (int mi = 0; mi < 2; ++mi) {
      const int r0 = wm * 32 + mi * 16 + ((lane >> 4) << 2);
      const f32x4 a = acc[mi][ni];
#pragma unroll
      for (int j = 0; j < 4; ++j) fs[(r0 + j) * 64 + lc] = f2b(a[j] + bias);
    }
  }
  BARRIER();
  {
    const int r = tid >> 2, c = (tid & 3) * 16;
    const uint4 w0 = *(const uint4*)(fs + r * 64 + c);
    const uint4 w1 = *(const uint4*)(fs + r * 64 + c + 8);
    unsigned short* op = Tout + (size_t)(vt * 64 + r) * 1024 + dt * 64 + c;
    *(uint4*)op = w0;
    *(uint4*)(op + 8) = w1;
  }
}

// ---------------- main fused kernel (round-3 structure + cvt_pk + bounce) ----------------
// BM=128 tokens, BN=128 out, BK=64; 512 thr (8 waves: wm4 x wn2, mi=2, ni=4)
__launch_bounds__(512, 4)
__global__ void moe_main(const int* __restrict__ X,
                         const unsigned short* __restrict__ T0,
                         const unsigned short* __restrict__ T1,
                         const unsigned short* __restrict__ W2T,
                         const float* __restrict__ G0,
                         const float* __restrict__ G1,
                         const float* __restrict__ b2v,
                         float* __restrict__ out) {
  __shared__ __align__(16) char smem[35840];
  unsigned short* At = (unsigned short*)smem;            // 16 KB, swizzled
  unsigned short* Bt = (unsigned short*)(smem + 16384);  // 16 KB, swizzled
  float* gl = (float*)(smem + 32768);                    // 2 KB
  int* xs0 = (int*)(smem + 34816);                       // 512 B
  int* xs1 = (int*)(smem + 35328);                       // 512 B

  const int tid = threadIdx.x, lane = tid & 63, wave = tid >> 6;
  const int wm = wave >> 1, wn = wave & 1;
  int bid = blockIdx.x;
  bid = (bid & 7) * 64 + (bid >> 3);  // XCD swizzle (512 % 8 == 0)
  const int b0 = bid * 128;

  if (tid < 128) {
    const int b = b0 + tid;
    const int x0 = X[2 * b], x1 = X[2 * b + 1];
    xs0[tid] = x0; xs1[tid] = x1;
    const float4 l0 = *(const float4*)(G0 + 4 * x0);
    const float4 l1 = *(const float4*)(G1 + 4 * x1);
    const float z0 = l0.x + l1.x, z1 = l0.y + l1.y;
    const float z2 = l0.z + l1.z, z3 = l0.w + l1.w;
    const float m = fmaxf(fmaxf(z0, z1), fmaxf(z2, z3));
    const float e0 = __expf(z0 - m), e1 = __expf(z1 - m);
    const float e2 = __expf(z2 - m), e3 = __expf(z3 - m);
    const float inv = __builtin_amdgcn_rcpf(e0 + e1 + e2 + e3);
    *(float4*)(&gl[4 * tid]) = make_float4(e0 * inv, e1 * inv, e2 * inv, e3 * inv);
  }
  __syncthreads();

  // staging coords: 4 thr/row, 32B each (A rows = tokens; Bt rows = out cols)
  const int arow = tid >> 2, ac = tid & 3;
  const int sx0 = xs0[arow], sx1 = xs1[arow];
  const float4 grow = *(const float4*)(&gl[4 * arow]);
  int wOff[2];
#pragma unroll
  for (int i = 0; i < 2; ++i)
    wOff[i] = arow * 128 + ((ac * 32 + i * 16) ^ ((arow & 7) << 4));

  // frag read offsets
  const int kq = (lane >> 4) * 16;
  int rAoff[2], rAsw[2], rBoff[4], rBsw[4];
#pragma unroll
  for (int mi = 0; mi < 2; ++mi) {
    const int ra = wm * 32 + mi * 16 + (lane & 15);
    rAoff[mi] = ra * 128; rAsw[mi] = (ra & 7) << 4;
  }
#pragma unroll
  for (int ni = 0; ni < 4; ++ni) {
    const int cb = wn * 64 + ni * 16 + (lane & 15);
    rBoff[ni] = cb * 128; rBsw[ni] = (cb & 7) << 4;
  }

  f32x4 acc[2][4] = {};
  uint4 ua[2], ub[2], bw[2];

  auto issueA = [&](int t) {
    const int e = t >> 4, d0 = (t & 15) << 6;
    const unsigned short* p0 = T0 + (((size_t)(e * 512 + sx0)) << 10) + d0 + ac * 16;
    const unsigned short* p1 = T1 + (((size_t)(e * 512 + sx1)) << 10) + d0 + ac * 16;
    ua[0] = *(const uint4*)p0; ua[1] = *(const uint4*)(p0 + 8);
    ub[0] = *(const uint4*)p1; ub[1] = *(const uint4*)(p1 + 8);
  };
  auto issueB = [&](int t) {
    const unsigned short* pb = W2T + (size_t)arow * 4096 + t * 64 + ac * 16;
    bw[0] = *(const uint4*)pb; bw[1] = *(const uint4*)(pb + 8);
  };
  auto gsel = [&](int t) -> float {
    const int e = t >> 4;
    return (e == 0) ? grow.x : (e == 1) ? grow.y : (e == 2) ? grow.z : grow.w;
  };

  issueA(0);
  issueB(0);
  for (int t = 0; t < 64; ++t) {
    const float g = gsel(t);
    uint4 sa[2];
#pragma unroll
    for (int i = 0; i < 2; ++i) {
      const unsigned int uu[4] = {ua[i].x, ua[i].y, ua[i].z, ua[i].w};
      const unsigned int vv[4] = {ub[i].x, ub[i].y, ub[i].z, ub[i].w};
      unsigned int w[4];
#pragma unroll
      for (int p = 0; p < 4; ++p) {
        const float f0 = bflo(uu[p]) + bflo(vv[p]);
        const float f1 = bfhi(uu[p]) + bfhi(vv[p]);
        const float s0 = g * f0 * __builtin_amdgcn_rcpf(1.f + __expf(-f0));
        const float s1 = g * f1 * __builtin_amdgcn_rcpf(1.f + __expf(-f1));
        w[p] = cvtpk(s0, s1);
      }
      sa[i] = uint4{w[0], w[1], w[2], w[3]};
    }
    if (t < 63) issueA(t + 1);   // stays in flight across raw barrier
    BARRIER();  // #1: all waves' frag reads of previous tile complete
    *(uint4*)((char*)At + wOff[0]) = sa[0];
    *(uint4*)((char*)At + wOff[1]) = sa[1];
    *(uint4*)((char*)Bt + wOff[0]) = bw[0];
    *(uint4*)((char*)Bt + wOff[1]) = bw[1];
    if (t < 63) issueB(t + 1);
    BARRIER();  // #2: writes visible
#pragma unroll
    for (int kk = 0; kk < 2; ++kk) {
      const int kb = kk * 64 + kq;
      short8 af[2], bfr[4];
#pragma unroll
      for (int mi = 0; mi < 2; ++mi)
        af[mi] = *(const short8*)((char*)At + rAoff[mi] + (kb ^ rAsw[mi]));
#pragma unroll
      for (int ni = 0; ni < 4; ++ni)
        bfr[ni] = *(const short8*)((char*)Bt + rBoff[ni] + (kb ^ rBsw[ni]));
#pragma unroll
      for (int mi = 0; mi < 2; ++mi)
#pragma unroll
        for (int ni = 0; ni < 4; ++ni)
          acc[mi][ni] = __builtin_amdgcn_mfma_f32_16x16x32_bf16(af[mi], bfr[ni], acc[mi][ni], 0, 0, 0);
    }
  }

  // ---- epilogue: + sum_e g_e*b2[e][o] into acc, then 4-pass LDS-bounce store ----
#pragma unroll
  for (int ni = 0; ni < 4; ++ni) {
    const int col = wn * 64 + ni * 16 + (lane & 15);
    const float c0 = b2v[col], c1 = b2v[128 + col];
    const float c2 = b2v[256 + col], c3 = b2v[384 + col];
#pragma unroll
    for (int mi = 0; mi < 2; ++mi) {
#pragma unroll
      for (int j = 0; j < 4; ++j) {
        const int row = wm * 32 + mi * 16 + ((lane >> 4) << 2) + j;
        const float4 g = *(const float4*)(&gl[4 * row]);
        acc[mi][ni][j] += g.x * c0 + g.y * c1 + g.z * c2 + g.w * c3;
      }
    }
  }
  float* fs = (float*)smem;  // 32 x 132 f32 = 16.9 KB (aliases At + Bt head; gl safe)
#pragma unroll
  for (int p = 0; p < 4; ++p) {
    BARRIER();  // last mfma frag reads (p=0) / previous pass readbacks (p>0) done
    if (wm == p) {
#pragma unroll
      for (int ni = 0; ni < 4; ++ni) {
        const int col = wn * 64 + ni * 16 + (lane & 15);
#pragma unroll
        for (int mi = 0; mi < 2; ++mi) {
          const int r0 = mi * 16 + ((lane >> 4) << 2);
          const f32x4 a = acc[mi][ni];
#pragma unroll
          for (int j = 0; j < 4; ++j) fs[(r0 + j) * 132 + col] = a[j];
        }
      }
    }
    BARRIER();
    const int r = tid >> 4, c0 = (tid & 15) * 8;
    const float4 v0 = *(const float4*)(fs + r * 132 + c0);
    const float4 v1 = *(const float4*)(fs + r * 132 + c0 + 4);
    float* op = out + (size_t)(b0 + p * 32 + r) * 128 + c0;
    *(float4*)op = v0;
    *(float4*)(op + 4) = v1;
  }
}

extern "C" void kernel_launch(void* const* d_in, const int* in_sizes, int n_in,
                              void* d_out, int out_size, void* d_ws, size_t ws_size,
                              hipStream_t stream) {
  const int*   X    = (const int*)  d_in[0];
  const float* emb0 = (const float*)d_in[1];
  const float* emb1 = (const float*)d_in[2];
  const float* W1   = (const float*)d_in[3];
  const float* b1   = (const float*)d_in[4];
  const float* W2   = (const float*)d_in[5];
  const float* b2   = (const float*)d_in[6];
  const float* Wg   = (const float*)d_in[7];
  const float* bg   = (const float*)d_in[8];
  float* out = (float*)d_out;

  char* ws = (char*)d_ws;
  const size_t MB = 1024 * 1024;
  unsigned short* T0  = (unsigned short*)(ws);             // 4 MB
  unsigned short* T1  = (unsigned short*)(ws + 4 * MB);    // 4 MB
  unsigned short* W2T = (unsigned short*)(ws + 8 * MB);    // 1 MB
  float* G0 = (float*)(ws + 9 * MB);                       // 8 KB
  float* G1 = (float*)(ws + 9 * MB + 8192);                // 8 KB
  unsigned short* E0  = (unsigned short*)(ws + 10 * MB);   // 1 MB
  unsigned short* E1  = (unsigned short*)(ws + 11 * MB);   // 1 MB
  unsigned short* W1T = (unsigned short*)(ws + 12 * MB);   // 16 MB

  hipLaunchKernelGGL(prep_all, dim3(3712), dim3(256), 0, stream,
                     emb0, emb1, Wg, bg, W2, W1, G0, G1, E0, E1, W2T, W1T);
  hipLaunchKernelGGL(build_tables, dim3(1024), dim3(256), 0, stream, E0, E1, W1T, b1, T0, T1);
  hipLaunchKernelGGL(moe_main, dim3(512), dim3(512), 0, stream, X, T0, T1, W2T, G0, G1, b2, out);
}